// Round 13
// baseline (1051.002 us; speedup 1.0000x reference)
//
#include <hip/hip_runtime.h>
#include <stdint.h>

#define DEVI static __device__ __forceinline__

typedef __attribute__((ext_vector_type(8))) __bf16 bf16x8;
typedef __attribute__((ext_vector_type(4))) float f32x4;

#define MFMA16(a, b, c) __builtin_amdgcn_mfma_f32_16x16x32_bf16((a), (b), (c), 0, 0, 0)

DEVI uint16_t f2bf(float f) {
  uint32_t u = __builtin_bit_cast(uint32_t, f);
  u += 0x7fffu + ((u >> 16) & 1u);   // RNE (no NaN inputs here)
  return (uint16_t)(u >> 16);
}

DEVI void gload16(const void* g, void* l) {
  __builtin_amdgcn_global_load_lds((const __attribute__((address_space(1))) void*)g,
                                   (__attribute__((address_space(3))) void*)l, 16, 0, 0);
}

#define BARRIER()                         \
  do {                                    \
    __builtin_amdgcn_sched_barrier(0);    \
    __builtin_amdgcn_s_barrier();         \
    __builtin_amdgcn_sched_barrier(0);    \
  } while (0)

#define LGKM0_FENCE()                                      \
  do {                                                     \
    asm volatile("s_waitcnt lgkmcnt(0)" ::: "memory");     \
    __builtin_amdgcn_sched_barrier(0);                     \
  } while (0)

// ---------------- f32 -> bf16 convert (8 elems/thread) ----------------
__global__ __launch_bounds__(256) void cvt_bf16(const float* __restrict__ in,
                                                uint16_t* __restrict__ out, long n) {
  long i = ((long)blockIdx.x * 256 + threadIdx.x) * 8;
  if (i >= n) return;
  float4 a = *(const float4*)(in + i);
  float4 b = *(const float4*)(in + i + 4);
  union { uint16_t u[8]; uint4 v; } r;
  r.u[0] = f2bf(a.x); r.u[1] = f2bf(a.y); r.u[2] = f2bf(a.z); r.u[3] = f2bf(a.w);
  r.u[4] = f2bf(b.x); r.u[5] = f2bf(b.y); r.u[6] = f2bf(b.z); r.u[7] = f2bf(b.w);
  *(uint4*)(out + i) = r.v;
}

// ---------------- W f32 [1024][1024] -> Wt bf16 [n][k] (transposed), 4 at once ----------------
struct W4 {
  const float* W[4];
  uint16_t* Wt[4];
};

__global__ __launch_bounds__(256) void wtrans4(W4 p) {
  __shared__ float t[64][65];
  const float* __restrict__ W = p.W[blockIdx.z];
  uint16_t* __restrict__ Wt = p.Wt[blockIdx.z];
  const int ti = blockIdx.y * 64, tj = blockIdx.x * 64;
  {
    int r = threadIdx.x >> 2, c0 = (threadIdx.x & 3) * 16;
#pragma unroll
    for (int i = 0; i < 16; i += 4) {
      float4 v = *(const float4*)(W + (size_t)(ti + r) * 1024 + tj + c0 + i);
      t[r][c0 + i + 0] = v.x; t[r][c0 + i + 1] = v.y;
      t[r][c0 + i + 2] = v.z; t[r][c0 + i + 3] = v.w;
    }
  }
  __syncthreads();
  {
    int c = threadIdx.x >> 2, r0 = (threadIdx.x & 3) * 16;
    union { uint16_t u[16]; uint4 v[2]; } b;
#pragma unroll
    for (int i = 0; i < 16; ++i) b.u[i] = f2bf(t[r0 + i][c]);
    uint16_t* dst = Wt + (size_t)(tj + c) * 1024 + ti + r0;
    *(uint4*)dst = b.v[0];
    *(uint4*)(dst + 8) = b.v[1];
  }
}

// ---------------- 128x128-tile GEMM, BK=32, 4 waves, 5 blocks/CU ----------------
// r9-family core moved to max occupancy: LDS 24KB = A dbuf 2x8KB @0 +
// B single 8KB @16384 (restaged in place). 5 resident blocks cover all
// latency (m114). 64B-row swizzle: read unit = lq ^ (lc>>2); stager source
// unit = (l&3)^((l>>4)&3) (same involution, gload dest linear).
// Coalesced bf16 epilogue through LDS (fixes 2x write amplification:
// measured WRITE_SIZE 131MB for 64MB C).
__global__ __launch_bounds__(256, 5) void gemm128(const uint16_t* __restrict__ A,
                                                  const uint16_t* __restrict__ Bt,
                                                  const float* __restrict__ bias,
                                                  void* __restrict__ C, int cf32) {
  __shared__ uint8_t lds[24576];
  const int tid = threadIdx.x;
  const int l = tid & 63, w = tid >> 6;
  const int wr = w >> 1, wc = w & 1;     // 2 x 2 wave grid, 64x64 per wave
  const int lc = l & 15, lq = l >> 4;

  // bijective XCD swizzle over 2048 blocks: XCD c owns m-panels [c*32,(c+1)*32)
  const int bid = blockIdx.y * 8 + blockIdx.x;
  const int swz = (bid & 7) * 256 + (bid >> 3);
  const size_t m0 = (size_t)(swz >> 3) * 128;
  const int n0 = (swz & 7) * 128;

  const uint8_t* Ab = (const uint8_t*)A + m0 * 2048;
  const uint8_t* Bb = (const uint8_t*)Bt + (size_t)n0 * 2048;

  // staging: chunk c = w*2+j = 1KB = 16 rows x 64B; lane l -> row c*16+(l>>2),
  // LDS unit l&3; source k-unit = (l&3) ^ ((l>>4)&3)  [inverse swizzle]
  const int srow_in = l >> 2;
  const int sug = (((l & 3) ^ ((l >> 4) & 3))) * 16;

  auto stageA = [&](int buf, int kt) {
#pragma unroll
    for (int j = 0; j < 2; ++j) {
      const int c = w * 2 + j;
      gload16(Ab + (size_t)(c * 16 + srow_in) * 2048 + kt * 64 + sug,
              lds + buf * 8192 + c * 1024);
    }
  };
  auto stageB = [&](int kt) {
#pragma unroll
    for (int j = 0; j < 2; ++j) {
      const int c = w * 2 + j;
      gload16(Bb + (size_t)(c * 16 + srow_in) * 2048 + kt * 64 + sug,
              lds + 16384 + c * 1024);
    }
  };

  // swizzled fragment reads: unit = lq ^ (lc>>2)
  const int ru = (lq ^ (lc >> 2)) * 16;
  auto ldsA = [&](int buf, int mi) -> bf16x8 {
    const int row = wr * 64 + mi * 16 + lc;
    return *(const bf16x8*)(lds + buf * 8192 + row * 64 + ru);
  };
  auto ldsB = [&](int ni) -> bf16x8 {
    const int row = wc * 64 + ni * 16 + lc;
    return *(const bf16x8*)(lds + 16384 + row * 64 + ru);
  };

  f32x4 acc[4][4] = {};

  // prologue: tile 0
  stageA(0, 0);
  stageB(0);
  asm volatile("s_waitcnt vmcnt(0)" ::: "memory");
  BARRIER();

  for (int t = 0; t < 32; ++t) {
    const int cur = t & 1;
    const bool more = (t + 1 < 32);

    // read B frags to regs, fence, then restage B in place + prefetch A
    bf16x8 bF[4];
#pragma unroll
    for (int ni = 0; ni < 4; ++ni) bF[ni] = ldsB(ni);
    LGKM0_FENCE();
    BARRIER();   // all waves' B reads complete before restage lands

    if (more) {
      stageB(t + 1);
      stageA(cur ^ 1, t + 1);
    }

    bf16x8 aF[4];
#pragma unroll
    for (int mi = 0; mi < 4; ++mi) aF[mi] = ldsA(cur, mi);
    __builtin_amdgcn_s_setprio(1);
#pragma unroll
    for (int mi = 0; mi < 4; ++mi)
#pragma unroll
      for (int ni = 0; ni < 4; ++ni)
        acc[mi][ni] = MFMA16(aF[mi], bF[ni], acc[mi][ni]);
    __builtin_amdgcn_s_setprio(0);

    if (more) {
      asm volatile("s_waitcnt vmcnt(0)" ::: "memory");  // t+1 landed (covered @5blk/CU)
      BARRIER();
    }
  }

  if (cf32) {
    // f32 C: 16 lanes x 4B = 64B full lines -- already coalesced
#pragma unroll
    for (int mi = 0; mi < 4; ++mi)
#pragma unroll
      for (int ni = 0; ni < 4; ++ni) {
        const int col = n0 + wc * 64 + ni * 16 + lc;
        const float bb = bias[col];
#pragma unroll
        for (int r = 0; r < 4; ++r) {
          const size_t row = m0 + wr * 64 + mi * 16 + lq * 4 + r;
          ((float*)C)[row * 1024 + col] = acc[mi][ni][r] + bb;
        }
      }
  } else {
    // bf16 C: stash to LDS, store 256B rows (fixes 2x write amplification)
    BARRIER();   // all MFMA LDS reads done; A-buffer region reused
    uint16_t* st = (uint16_t*)lds;   // 64 packed rows x 128 cols = 16KB
#pragma unroll
    for (int ch = 0; ch < 2; ++ch) {
#pragma unroll
      for (int mi2 = 0; mi2 < 2; ++mi2) {
        const int mi = ch * 2 + mi2;
#pragma unroll
        for (int ni = 0; ni < 4; ++ni) {
          const int col = wc * 64 + ni * 16 + lc;
          const float bb = bias[n0 + col];
#pragma unroll
          for (int r = 0; r < 4; ++r) {
            const int prow = wr * 32 + mi2 * 16 + lq * 4 + r;
            st[prow * 128 + col] = f2bf(acc[mi][ni][r] + bb);
          }
        }
      }
      __syncthreads();
#pragma unroll
      for (int i = 0; i < 4; ++i) {
        const int p = (tid >> 4) + i * 16;       // packed row 0..63
        const int c16 = tid & 15;                // 16B chunk
        const size_t grow = m0 + (p >> 5) * 64 + ch * 32 + (p & 31);
        *(uint4*)((uint8_t*)C + grow * 2048 + n0 * 2 + c16 * 16) =
            *(const uint4*)((const uint8_t*)st + p * 256 + c16 * 16);
      }
      if (ch == 0) __syncthreads();
    }
  }
}

// ---------------- block-diagonal attention ----------------
__global__ __launch_bounds__(256) void attn(const uint16_t* __restrict__ Qh,
                                            const uint16_t* __restrict__ Kh,
                                            const uint16_t* __restrict__ Vh,
                                            uint16_t* __restrict__ Oh,
                                            float* __restrict__ Wlast) {
  __shared__ uint16_t Ks[128][72];
  __shared__ uint16_t Vt[64][136];
  __shared__ uint16_t Ps[128][136];

  const int blk = blockIdx.x;
  const int b = blk >> 10;
  const int h = (blk >> 6) & 15;
  const int g = blk & 63;
  const size_t rowbase = (size_t)b * 8192 + (size_t)g * 128;
  const int colbase = h * 64;

  const int tid = threadIdx.x, lane = tid & 63, wv = tid >> 6;
  const int lc = lane & 15, lq = lane >> 4;
  const int m0 = wv * 32;

  {
    const int r = tid >> 1, hf = (tid & 1) * 32;
    const uint16_t* ksrc = Kh + (rowbase + r) * 1024 + colbase + hf;
    const uint16_t* vsrc = Vh + (rowbase + r) * 1024 + colbase + hf;
    union { uint16_t u[32]; uint4 v[4]; } kk, vb;
#pragma unroll
    for (int i = 0; i < 4; ++i) kk.v[i] = *(const uint4*)(ksrc + i * 8);
#pragma unroll
    for (int i = 0; i < 4; ++i) vb.v[i] = *(const uint4*)(vsrc + i * 8);
#pragma unroll
    for (int i = 0; i < 4; ++i) *(uint4*)&Ks[r][hf + i * 8] = kk.v[i];
#pragma unroll
    for (int j = 0; j < 32; ++j) Vt[hf + j][r] = vb.u[j];
  }

  bf16x8 aq[2][2];
#pragma unroll
  for (int mi = 0; mi < 2; ++mi)
#pragma unroll
    for (int ks = 0; ks < 2; ++ks)
      aq[mi][ks] = *(const bf16x8*)(Qh + (rowbase + m0 + mi * 16 + lc) * 1024 +
                                    colbase + ks * 32 + lq * 8);

  __syncthreads();

  f32x4 sacc[2][8] = {};
#pragma unroll
  for (int ks = 0; ks < 2; ++ks) {
#pragma unroll
    for (int ni = 0; ni < 8; ++ni) {
      bf16x8 bk = *(const bf16x8*)&Ks[ni * 16 + lc][ks * 32 + lq * 8];
      sacc[0][ni] = MFMA16(aq[0][ks], bk, sacc[0][ni]);
      sacc[1][ni] = MFMA16(aq[1][ks], bk, sacc[1][ni]);
    }
  }

  const float scale = 0.125f;
  float mx[2][4], sm[2][4];
#pragma unroll
  for (int mi = 0; mi < 2; ++mi)
#pragma unroll
    for (int r = 0; r < 4; ++r) {
      float m = -1e30f;
#pragma unroll
      for (int ni = 0; ni < 8; ++ni) m = fmaxf(m, sacc[mi][ni][r]);
      m = fmaxf(m, __shfl_xor(m, 1));
      m = fmaxf(m, __shfl_xor(m, 2));
      m = fmaxf(m, __shfl_xor(m, 4));
      m = fmaxf(m, __shfl_xor(m, 8));
      mx[mi][r] = m * scale;
    }
#pragma unroll
  for (int mi = 0; mi < 2; ++mi)
#pragma unroll
    for (int ni = 0; ni < 8; ++ni)
#pragma unroll
      for (int r = 0; r < 4; ++r)
        sacc[mi][ni][r] = __expf(sacc[mi][ni][r] * scale - mx[mi][r]);
#pragma unroll
  for (int mi = 0; mi < 2; ++mi)
#pragma unroll
    for (int r = 0; r < 4; ++r) {
      float s = 0.f;
#pragma unroll
      for (int ni = 0; ni < 8; ++ni) s += sacc[mi][ni][r];
      s += __shfl_xor(s, 1); s += __shfl_xor(s, 2);
      s += __shfl_xor(s, 4); s += __shfl_xor(s, 8);
      sm[mi][r] = 1.0f / s;
    }

#pragma unroll
  for (int mi = 0; mi < 2; ++mi)
#pragma unroll
    for (int ni = 0; ni < 8; ++ni)
#pragma unroll
      for (int r = 0; r < 4; ++r) {
        float wgt = sacc[mi][ni][r] * sm[mi][r];
        sacc[mi][ni][r] = wgt;
        Ps[m0 + mi * 16 + lq * 4 + r][ni * 16 + lc] = f2bf(wgt);
      }
  if (g == 63) {
    float* wl = Wlast + (size_t)(b * 16 + h) * 16384;
#pragma unroll
    for (int mi = 0; mi < 2; ++mi)
#pragma unroll
      for (int ni = 0; ni < 8; ++ni)
#pragma unroll
        for (int r = 0; r < 4; ++r)
          wl[(size_t)(m0 + mi * 16 + lq * 4 + r) * 128 + ni * 16 + lc] =
              sacc[mi][ni][r];
  }
  __syncthreads();

  f32x4 oacc[2][4] = {};
#pragma unroll
  for (int ks = 0; ks < 4; ++ks) {
    bf16x8 ap[2], bq[4];
#pragma unroll
    for (int mi = 0; mi < 2; ++mi)
      ap[mi] = *(const bf16x8*)&Ps[m0 + mi * 16 + lc][ks * 32 + lq * 8];
#pragma unroll
    for (int ni = 0; ni < 4; ++ni)
      bq[ni] = *(const bf16x8*)&Vt[ni * 16 + lc][ks * 32 + lq * 8];
#pragma unroll
    for (int mi = 0; mi < 2; ++mi)
#pragma unroll
      for (int ni = 0; ni < 4; ++ni)
        oacc[mi][ni] = MFMA16(ap[mi], bq[ni], oacc[mi][ni]);
  }

  // coalesced O store: stash bf16 O into Ks region (free after QK^T),
  // then write 128B rows (8 lanes x 16B) -- fixes 32B-chunk amplification
  uint16_t* os = &Ks[0][0];   // 128 rows x 64 cols = 16KB <= 18KB
#pragma unroll
  for (int mi = 0; mi < 2; ++mi)
#pragma unroll
    for (int ni = 0; ni < 4; ++ni)
#pragma unroll
      for (int r = 0; r < 4; ++r)
        os[(m0 + mi * 16 + lq * 4 + r) * 64 + ni * 16 + lc] = f2bf(oacc[mi][ni][r]);
  __syncthreads();
#pragma unroll
  for (int i = 0; i < 4; ++i) {
    const int row = i * 32 + (tid >> 3);
    const int c8 = tid & 7;
    *(uint4*)(Oh + (rowbase + row) * 1024 + colbase + c8 * 8) =
        *(const uint4*)(os + row * 64 + c8 * 8);
  }
}

extern "C" void kernel_launch(void* const* d_in, const int* in_sizes, int n_in,
                              void* d_out, int out_size, void* d_ws, size_t ws_size,
                              hipStream_t stream) {
  (void)in_sizes; (void)n_in; (void)out_size; (void)ws_size;
  const float* q  = (const float*)d_in[0];
  const float* k  = (const float*)d_in[1];
  const float* v  = (const float*)d_in[2];
  const float* Wq = (const float*)d_in[3];
  const float* bq = (const float*)d_in[4];
  const float* Wk = (const float*)d_in[5];
  const float* bk = (const float*)d_in[6];
  const float* Wv = (const float*)d_in[7];
  const float* bv = (const float*)d_in[8];
  const float* Wo = (const float*)d_in[9];
  const float* bo = (const float*)d_in[10];

  uint8_t* ws = (uint8_t*)d_ws;
  const size_t WSZ = (size_t)1024 * 1024 * 2;   // 2 MB per transposed weight
  const size_t TSZ = (size_t)32768 * 1024 * 2;  // 64 MB per bf16 activation
  uint16_t* Wtq = (uint16_t*)(ws + 0 * WSZ);
  uint16_t* Wtk = (uint16_t*)(ws + 1 * WSZ);
  uint16_t* Wtv = (uint16_t*)(ws + 2 * WSZ);
  uint16_t* Wto = (uint16_t*)(ws + 3 * WSZ);
  uint16_t* Qh  = (uint16_t*)(ws + 4 * WSZ);
  uint16_t* Khp = (uint16_t*)(ws + 4 * WSZ + 1 * TSZ);
  uint16_t* Vhp = (uint16_t*)(ws + 4 * WSZ + 2 * TSZ);
  uint16_t* Xs  = (uint16_t*)(ws + 4 * WSZ + 3 * TSZ);  // staging / attn-out

  W4 wt;
  wt.W[0] = Wq; wt.W[1] = Wk; wt.W[2] = Wv; wt.W[3] = Wo;
  wt.Wt[0] = Wtq; wt.Wt[1] = Wtk; wt.Wt[2] = Wtv; wt.Wt[3] = Wto;
  wtrans4<<<dim3(16, 16, 4), 256, 0, stream>>>(wt);

  const long NE = (long)32768 * 1024;
  const dim3 gg(8, 256), gb(256);
  cvt_bf16<<<16384, 256, 0, stream>>>(q, Xs, NE);
  gemm128<<<gg, gb, 0, stream>>>(Xs, Wtq, bq, Qh, 0);
  cvt_bf16<<<16384, 256, 0, stream>>>(k, Xs, NE);
  gemm128<<<gg, gb, 0, stream>>>(Xs, Wtk, bk, Khp, 0);
  cvt_bf16<<<16384, 256, 0, stream>>>(v, Xs, NE);
  gemm128<<<gg, gb, 0, stream>>>(Xs, Wtv, bv, Vhp, 0);

  float* outp = (float*)d_out;
  attn<<<4096, 256, 0, stream>>>(Qh, Khp, Vhp, Xs, outp + (size_t)32768 * 1024);
  gemm128<<<gg, gb, 0, stream>>>(Xs, Wto, bo, outp, 1);
}

// Round 14
// 477.556 us; speedup vs baseline: 2.2008x; 2.2008x over previous
//
#include <hip/hip_runtime.h>
#include <stdint.h>

#define DEVI static __device__ __forceinline__

typedef __attribute__((ext_vector_type(8))) __bf16 bf16x8;
typedef __attribute__((ext_vector_type(4))) float f32x4;

#define MFMA16(a, b, c) __builtin_amdgcn_mfma_f32_16x16x32_bf16((a), (b), (c), 0, 0, 0)

DEVI uint16_t f2bf(float f) {
  uint32_t u = __builtin_bit_cast(uint32_t, f);
  u += 0x7fffu + ((u >> 16) & 1u);   // RNE (no NaN inputs here)
  return (uint16_t)(u >> 16);
}

DEVI void gload16(const void* g, void* l) {
  __builtin_amdgcn_global_load_lds((const __attribute__((address_space(1))) void*)g,
                                   (__attribute__((address_space(3))) void*)l, 16, 0, 0);
}

#define BARRIER()                         \
  do {                                    \
    __builtin_amdgcn_sched_barrier(0);    \
    __builtin_amdgcn_s_barrier();         \
    __builtin_amdgcn_sched_barrier(0);    \
  } while (0)

#define LGKM0_FENCE()                                      \
  do {                                                     \
    asm volatile("s_waitcnt lgkmcnt(0)" ::: "memory");     \
    __builtin_amdgcn_sched_barrier(0);                     \
  } while (0)

// ---------------- f32 -> bf16 convert (8 elems/thread) ----------------
__global__ __launch_bounds__(256) void cvt_bf16(const float* __restrict__ in,
                                                uint16_t* __restrict__ out, long n) {
  long i = ((long)blockIdx.x * 256 + threadIdx.x) * 8;
  if (i >= n) return;
  float4 a = *(const float4*)(in + i);
  float4 b = *(const float4*)(in + i + 4);
  union { uint16_t u[8]; uint4 v; } r;
  r.u[0] = f2bf(a.x); r.u[1] = f2bf(a.y); r.u[2] = f2bf(a.z); r.u[3] = f2bf(a.w);
  r.u[4] = f2bf(b.x); r.u[5] = f2bf(b.y); r.u[6] = f2bf(b.z); r.u[7] = f2bf(b.w);
  *(uint4*)(out + i) = r.v;
}

// ---------------- W f32 [1024][1024] -> Wt bf16 [n][k] (transposed), 4 at once ----------------
struct W4 {
  const float* W[4];
  uint16_t* Wt[4];
};

__global__ __launch_bounds__(256) void wtrans4(W4 p) {
  __shared__ float t[64][65];
  const float* __restrict__ W = p.W[blockIdx.z];
  uint16_t* __restrict__ Wt = p.Wt[blockIdx.z];
  const int ti = blockIdx.y * 64, tj = blockIdx.x * 64;
  {
    int r = threadIdx.x >> 2, c0 = (threadIdx.x & 3) * 16;
#pragma unroll
    for (int i = 0; i < 16; i += 4) {
      float4 v = *(const float4*)(W + (size_t)(ti + r) * 1024 + tj + c0 + i);
      t[r][c0 + i + 0] = v.x; t[r][c0 + i + 1] = v.y;
      t[r][c0 + i + 2] = v.z; t[r][c0 + i + 3] = v.w;
    }
  }
  __syncthreads();
  {
    int c = threadIdx.x >> 2, r0 = (threadIdx.x & 3) * 16;
    union { uint16_t u[16]; uint4 v[2]; } b;
#pragma unroll
    for (int i = 0; i < 16; ++i) b.u[i] = f2bf(t[r0 + i][c]);
    uint16_t* dst = Wt + (size_t)(tj + c) * 1024 + ti + r0;
    *(uint4*)dst = b.v[0];
    *(uint4*)(dst + 8) = b.v[1];
  }
}

// ---------------- 128x128-tile GEMM, BK=64, 4 waves, 3 blocks/CU (r9 core) ----------------
// LDS 48KB: A dbuf 2x16KB @0 + B single 16KB @32768 (restaged in place).
// Per K-tile(64): read B-frags -> lgkm0 -> BAR -> restage B + A(t+1) ->
// MFMA -> vmcnt(0) -> BAR (drain free at 3 blocks/CU, m114 / r9-proven).
// Swizzle (proven, 0 conflicts): LDS[row][u16] = G[row][u16 ^ (row&7)].
// bf16 epilogue: LDS repack (rows padded to 132 elems -> lq-groups hit bank
// offsets {0,8,16,24}, conflict-free) then 256B coalesced stores — fixes the
// measured 2x write amplification (131MB HBM writes for 64MB C).
__global__ __launch_bounds__(256, 3) void gemm128(const uint16_t* __restrict__ A,
                                                  const uint16_t* __restrict__ Bt,
                                                  const float* __restrict__ bias,
                                                  void* __restrict__ C, int cf32) {
  __shared__ uint8_t lds[49152];
  const int tid = threadIdx.x;
  const int l = tid & 63, w = tid >> 6;
  const int wr = w >> 1, wc = w & 1;     // 2 x 2 wave grid, 64x64 per wave
  const int lc = l & 15, lq = l >> 4;

  // bijective XCD swizzle over 2048 blocks: XCD c owns m-panels [c*32,(c+1)*32)
  const int bid = blockIdx.y * 8 + blockIdx.x;
  const int swz = (bid & 7) * 256 + (bid >> 3);
  const size_t m0 = (size_t)(swz >> 3) * 128;
  const int n0 = (swz & 7) * 128;

  const uint8_t* Ab = (const uint8_t*)A + m0 * 2048;
  const uint8_t* Bb = (const uint8_t*)Bt + (size_t)n0 * 2048;

  // staging: chunk c = w*4+j = 1KB = 8 rows x 128B; lane covers 16B
  const int lrow = l >> 3;
  const int susw = ((l & 7) ^ lrow) * 16;  // inverse-swizzled source unit

  auto stageA = [&](int buf, int kt) {
#pragma unroll
    for (int j = 0; j < 4; ++j) {
      const int c = w * 4 + j;
      gload16(Ab + (size_t)(c * 8 + lrow) * 2048 + kt * 128 + susw,
              lds + buf * 16384 + c * 1024);
    }
  };
  auto stageB = [&](int kt) {
#pragma unroll
    for (int j = 0; j < 4; ++j) {
      const int c = w * 4 + j;
      gload16(Bb + (size_t)(c * 8 + lrow) * 2048 + kt * 128 + susw,
              lds + 32768 + c * 1024);
    }
  };

  auto ldsA = [&](int buf, int mi, int kk) -> bf16x8 {
    const int row = wr * 64 + mi * 16 + lc;
    const int u = ((kk * 4 + lq) ^ (row & 7)) * 16;
    return *(const bf16x8*)(lds + buf * 16384 + row * 128 + u);
  };
  auto ldsB = [&](int ni, int kk) -> bf16x8 {
    const int row = wc * 64 + ni * 16 + lc;
    const int u = ((kk * 4 + lq) ^ (row & 7)) * 16;
    return *(const bf16x8*)(lds + 32768 + row * 128 + u);
  };

  f32x4 acc[4][4] = {};

  // prologue: tile 0
  stageA(0, 0);
  stageB(0);
  asm volatile("s_waitcnt vmcnt(0)" ::: "memory");
  BARRIER();

  for (int t = 0; t < 16; ++t) {
    const int cur = t & 1;
    const bool more = (t + 1 < 16);

    // read ALL B-frags to regs (B buffer is restaged in place below)
    bf16x8 bF[4][2];
#pragma unroll
    for (int ni = 0; ni < 4; ++ni)
#pragma unroll
      for (int kk = 0; kk < 2; ++kk) bF[ni][kk] = ldsB(ni, kk);
    LGKM0_FENCE();
    BARRIER();   // every wave's B-reads complete before any restage lands

    if (more) {
      stageB(t + 1);            // in-place (safe: B now in regs block-wide)
      stageA(cur ^ 1, t + 1);   // alt buffer
    }

#pragma unroll
    for (int kk = 0; kk < 2; ++kk) {
      bf16x8 aF[4];
#pragma unroll
      for (int mi = 0; mi < 4; ++mi) aF[mi] = ldsA(cur, mi, kk);
      __builtin_amdgcn_s_setprio(1);
#pragma unroll
      for (int mi = 0; mi < 4; ++mi)
#pragma unroll
        for (int ni = 0; ni < 4; ++ni)
          acc[mi][ni] = MFMA16(aF[mi], bF[ni][kk], acc[mi][ni]);
      __builtin_amdgcn_s_setprio(0);
    }

    if (more) {
      asm volatile("s_waitcnt vmcnt(0)" ::: "memory");  // t+1 tiles landed
      BARRIER();
    }
  }

  if (cf32) {
    // f32 C: 16 lanes x 4B = 64B lines -- already coalesced
#pragma unroll
    for (int mi = 0; mi < 4; ++mi)
#pragma unroll
      for (int ni = 0; ni < 4; ++ni) {
        const int col = n0 + wc * 64 + ni * 16 + lc;
        const float bb = bias[col];
#pragma unroll
        for (int r = 0; r < 4; ++r) {
          const size_t row = m0 + wr * 64 + mi * 16 + lq * 4 + r;
          ((float*)C)[row * 1024 + col] = acc[mi][ni][r] + bb;
        }
      }
  } else {
    // bf16 C via LDS repack; rows padded to 132 elems (conflict-free:
    // lq stride = 4*264B -> bank offsets {0,8,16,24}); 256B stores.
    BARRIER();   // all MFMA reads done; LDS reused
    uint16_t* st = (uint16_t*)lds;   // 64 rows x 132 = 16.9KB
#pragma unroll
    for (int ch = 0; ch < 2; ++ch) {
#pragma unroll
      for (int mi2 = 0; mi2 < 2; ++mi2) {
        const int mi = ch * 2 + mi2;
#pragma unroll
        for (int ni = 0; ni < 4; ++ni) {
          const int col = wc * 64 + ni * 16 + lc;
          const float bb = bias[n0 + col];
#pragma unroll
          for (int r = 0; r < 4; ++r) {
            const int prow = wr * 32 + mi2 * 16 + lq * 4 + r;
            st[prow * 132 + col] = f2bf(acc[mi][ni][r] + bb);
          }
        }
      }
      __syncthreads();
#pragma unroll
      for (int i = 0; i < 4; ++i) {
        const int p = (tid >> 4) + i * 16;       // packed row 0..63
        const int c16 = tid & 15;                // 16B chunk within 256B row
        const size_t grow = m0 + (p >> 5) * 64 + ch * 32 + (p & 31);
        *(uint4*)((uint8_t*)C + grow * 2048 + n0 * 2 + c16 * 16) =
            *(const uint4*)((const uint8_t*)st + p * 264 + c16 * 16);
      }
      if (ch == 0) __syncthreads();
    }
  }
}

// ---------------- block-diagonal attention ----------------
__global__ __launch_bounds__(256) void attn(const uint16_t* __restrict__ Qh,
                                            const uint16_t* __restrict__ Kh,
                                            const uint16_t* __restrict__ Vh,
                                            uint16_t* __restrict__ Oh,
                                            float* __restrict__ Wlast) {
  __shared__ uint16_t Ks[128][72];
  __shared__ uint16_t Vt[64][136];
  __shared__ uint16_t Ps[128][136];

  const int blk = blockIdx.x;
  const int b = blk >> 10;
  const int h = (blk >> 6) & 15;
  const int g = blk & 63;
  const size_t rowbase = (size_t)b * 8192 + (size_t)g * 128;
  const int colbase = h * 64;

  const int tid = threadIdx.x, lane = tid & 63, wv = tid >> 6;
  const int lc = lane & 15, lq = lane >> 4;
  const int m0 = wv * 32;

  {
    const int r = tid >> 1, hf = (tid & 1) * 32;
    const uint16_t* ksrc = Kh + (rowbase + r) * 1024 + colbase + hf;
    const uint16_t* vsrc = Vh + (rowbase + r) * 1024 + colbase + hf;
    union { uint16_t u[32]; uint4 v[4]; } kk, vb;
#pragma unroll
    for (int i = 0; i < 4; ++i) kk.v[i] = *(const uint4*)(ksrc + i * 8);
#pragma unroll
    for (int i = 0; i < 4; ++i) vb.v[i] = *(const uint4*)(vsrc + i * 8);
#pragma unroll
    for (int i = 0; i < 4; ++i) *(uint4*)&Ks[r][hf + i * 8] = kk.v[i];
#pragma unroll
    for (int j = 0; j < 32; ++j) Vt[hf + j][r] = vb.u[j];
  }

  bf16x8 aq[2][2];
#pragma unroll
  for (int mi = 0; mi < 2; ++mi)
#pragma unroll
    for (int ks = 0; ks < 2; ++ks)
      aq[mi][ks] = *(const bf16x8*)(Qh + (rowbase + m0 + mi * 16 + lc) * 1024 +
                                    colbase + ks * 32 + lq * 8);

  __syncthreads();

  f32x4 sacc[2][8] = {};
#pragma unroll
  for (int ks = 0; ks < 2; ++ks) {
#pragma unroll
    for (int ni = 0; ni < 8; ++ni) {
      bf16x8 bk = *(const bf16x8*)&Ks[ni * 16 + lc][ks * 32 + lq * 8];
      sacc[0][ni] = MFMA16(aq[0][ks], bk, sacc[0][ni]);
      sacc[1][ni] = MFMA16(aq[1][ks], bk, sacc[1][ni]);
    }
  }

  const float scale = 0.125f;
  float mx[2][4], sm[2][4];
#pragma unroll
  for (int mi = 0; mi < 2; ++mi)
#pragma unroll
    for (int r = 0; r < 4; ++r) {
      float m = -1e30f;
#pragma unroll
      for (int ni = 0; ni < 8; ++ni) m = fmaxf(m, sacc[mi][ni][r]);
      m = fmaxf(m, __shfl_xor(m, 1));
      m = fmaxf(m, __shfl_xor(m, 2));
      m = fmaxf(m, __shfl_xor(m, 4));
      m = fmaxf(m, __shfl_xor(m, 8));
      mx[mi][r] = m * scale;
    }
#pragma unroll
  for (int mi = 0; mi < 2; ++mi)
#pragma unroll
    for (int ni = 0; ni < 8; ++ni)
#pragma unroll
      for (int r = 0; r < 4; ++r)
        sacc[mi][ni][r] = __expf(sacc[mi][ni][r] * scale - mx[mi][r]);
#pragma unroll
  for (int mi = 0; mi < 2; ++mi)
#pragma unroll
    for (int r = 0; r < 4; ++r) {
      float s = 0.f;
#pragma unroll
      for (int ni = 0; ni < 8; ++ni) s += sacc[mi][ni][r];
      s += __shfl_xor(s, 1); s += __shfl_xor(s, 2);
      s += __shfl_xor(s, 4); s += __shfl_xor(s, 8);
      sm[mi][r] = 1.0f / s;
    }

#pragma unroll
  for (int mi = 0; mi < 2; ++mi)
#pragma unroll
    for (int ni = 0; ni < 8; ++ni)
#pragma unroll
      for (int r = 0; r < 4; ++r) {
        float wgt = sacc[mi][ni][r] * sm[mi][r];
        sacc[mi][ni][r] = wgt;
        Ps[m0 + mi * 16 + lq * 4 + r][ni * 16 + lc] = f2bf(wgt);
      }
  if (g == 63) {
    float* wl = Wlast + (size_t)(b * 16 + h) * 16384;
#pragma unroll
    for (int mi = 0; mi < 2; ++mi)
#pragma unroll
      for (int ni = 0; ni < 8; ++ni)
#pragma unroll
        for (int r = 0; r < 4; ++r)
          wl[(size_t)(m0 + mi * 16 + lq * 4 + r) * 128 + ni * 16 + lc] =
              sacc[mi][ni][r];
  }
  __syncthreads();

  f32x4 oacc[2][4] = {};
#pragma unroll
  for (int ks = 0; ks < 4; ++ks) {
    bf16x8 ap[2], bq[4];
#pragma unroll
    for (int mi = 0; mi < 2; ++mi)
      ap[mi] = *(const bf16x8*)&Ps[m0 + mi * 16 + lc][ks * 32 + lq * 8];
#pragma unroll
    for (int ni = 0; ni < 4; ++ni)
      bq[ni] = *(const bf16x8*)&Vt[ni * 16 + lc][ks * 32 + lq * 8];
#pragma unroll
    for (int mi = 0; mi < 2; ++mi)
#pragma unroll
      for (int ni = 0; ni < 4; ++ni)
        oacc[mi][ni] = MFMA16(ap[mi], bq[ni], oacc[mi][ni]);
  }

  // coalesced O store: stash bf16 O into Ks region (dead after QK^T),
  // then write 128B rows (8 lanes x 16B)
  __syncthreads();
  uint16_t* os = &Ks[0][0];   // 128 rows x 64 cols = 16KB (Ks is 18KB)
#pragma unroll
  for (int mi = 0; mi < 2; ++mi)
#pragma unroll
    for (int ni = 0; ni < 4; ++ni)
#pragma unroll
      for (int r = 0; r < 4; ++r)
        os[(m0 + mi * 16 + lq * 4 + r) * 64 + ni * 16 + lc] = f2bf(oacc[mi][ni][r]);
  __syncthreads();
#pragma unroll
  for (int i = 0; i < 4; ++i) {
    const int row = i * 32 + (tid >> 3);
    const int c8 = tid & 7;
    *(uint4*)(Oh + (rowbase + row) * 1024 + colbase + c8 * 8) =
        *(const uint4*)(os + row * 64 + c8 * 8);
  }
}

extern "C" void kernel_launch(void* const* d_in, const int* in_sizes, int n_in,
                              void* d_out, int out_size, void* d_ws, size_t ws_size,
                              hipStream_t stream) {
  (void)in_sizes; (void)n_in; (void)out_size; (void)ws_size;
  const float* q  = (const float*)d_in[0];
  const float* k  = (const float*)d_in[1];
  const float* v  = (const float*)d_in[2];
  const float* Wq = (const float*)d_in[3];
  const float* bq = (const float*)d_in[4];
  const float* Wk = (const float*)d_in[5];
  const float* bk = (const float*)d_in[6];
  const float* Wv = (const float*)d_in[7];
  const float* bv = (const float*)d_in[8];
  const float* Wo = (const float*)d_in[9];
  const float* bo = (const float*)d_in[10];

  uint8_t* ws = (uint8_t*)d_ws;
  const size_t WSZ = (size_t)1024 * 1024 * 2;   // 2 MB per transposed weight
  const size_t TSZ = (size_t)32768 * 1024 * 2;  // 64 MB per bf16 activation
  uint16_t* Wtq = (uint16_t*)(ws + 0 * WSZ);
  uint16_t* Wtk = (uint16_t*)(ws + 1 * WSZ);
  uint16_t* Wtv = (uint16_t*)(ws + 2 * WSZ);
  uint16_t* Wto = (uint16_t*)(ws + 3 * WSZ);
  uint16_t* Qh  = (uint16_t*)(ws + 4 * WSZ);
  uint16_t* Khp = (uint16_t*)(ws + 4 * WSZ + 1 * TSZ);
  uint16_t* Vhp = (uint16_t*)(ws + 4 * WSZ + 2 * TSZ);
  uint16_t* Xs  = (uint16_t*)(ws + 4 * WSZ + 3 * TSZ);  // staging / attn-out

  W4 wt;
  wt.W[0] = Wq; wt.W[1] = Wk; wt.W[2] = Wv; wt.W[3] = Wo;
  wt.Wt[0] = Wtq; wt.Wt[1] = Wtk; wt.Wt[2] = Wtv; wt.Wt[3] = Wto;
  wtrans4<<<dim3(16, 16, 4), 256, 0, stream>>>(wt);

  const long NE = (long)32768 * 1024;
  const dim3 gg(8, 256), gb(256);
  cvt_bf16<<<16384, 256, 0, stream>>>(q, Xs, NE);
  gemm128<<<gg, gb, 0, stream>>>(Xs, Wtq, bq, Qh, 0);
  cvt_bf16<<<16384, 256, 0, stream>>>(k, Xs, NE);
  gemm128<<<gg, gb, 0, stream>>>(Xs, Wtk, bk, Khp, 0);
  cvt_bf16<<<16384, 256, 0, stream>>>(v, Xs, NE);
  gemm128<<<gg, gb, 0, stream>>>(Xs, Wtv, bv, Vhp, 0);

  float* outp = (float*)d_out;
  attn<<<4096, 256, 0, stream>>>(Qh, Khp, Vhp, Xs, outp + (size_t)32768 * 1024);
  gemm128<<<gg, gb, 0, stream>>>(Xs, Wto, bo, outp, 1);
}

// Round 15
// 468.124 us; speedup vs baseline: 2.2451x; 1.0201x over previous
//
#include <hip/hip_runtime.h>
#include <stdint.h>

#define DEVI static __device__ __forceinline__

typedef __attribute__((ext_vector_type(8))) __bf16 bf16x8;
typedef __attribute__((ext_vector_type(4))) float f32x4;

#define MFMA16(a, b, c) __builtin_amdgcn_mfma_f32_16x16x32_bf16((a), (b), (c), 0, 0, 0)

DEVI uint16_t f2bf(float f) {
  uint32_t u = __builtin_bit_cast(uint32_t, f);
  u += 0x7fffu + ((u >> 16) & 1u);   // RNE (no NaN inputs here)
  return (uint16_t)(u >> 16);
}

DEVI void gload16(const void* g, void* l) {
  __builtin_amdgcn_global_load_lds((const __attribute__((address_space(1))) void*)g,
                                   (__attribute__((address_space(3))) void*)l, 16, 0, 0);
}

#define BARRIER()                         \
  do {                                    \
    __builtin_amdgcn_sched_barrier(0);    \
    __builtin_amdgcn_s_barrier();         \
    __builtin_amdgcn_sched_barrier(0);    \
  } while (0)

#define LGKM0_FENCE()                                      \
  do {                                                     \
    asm volatile("s_waitcnt lgkmcnt(0)" ::: "memory");     \
    __builtin_amdgcn_sched_barrier(0);                     \
  } while (0)

// ---------------- f32 -> bf16 convert (8 elems/thread) ----------------
__global__ __launch_bounds__(256) void cvt_bf16(const float* __restrict__ in,
                                                uint16_t* __restrict__ out, long n) {
  long i = ((long)blockIdx.x * 256 + threadIdx.x) * 8;
  if (i >= n) return;
  float4 a = *(const float4*)(in + i);
  float4 b = *(const float4*)(in + i + 4);
  union { uint16_t u[8]; uint4 v; } r;
  r.u[0] = f2bf(a.x); r.u[1] = f2bf(a.y); r.u[2] = f2bf(a.z); r.u[3] = f2bf(a.w);
  r.u[4] = f2bf(b.x); r.u[5] = f2bf(b.y); r.u[6] = f2bf(b.z); r.u[7] = f2bf(b.w);
  *(uint4*)(out + i) = r.v;
}

// ---------------- W f32 [1024][1024] -> Wt bf16 [n][k] (transposed), 4 at once ----------------
struct W4 {
  const float* W[4];
  uint16_t* Wt[4];
};

__global__ __launch_bounds__(256) void wtrans4(W4 p) {
  __shared__ float t[64][65];
  const float* __restrict__ W = p.W[blockIdx.z];
  uint16_t* __restrict__ Wt = p.Wt[blockIdx.z];
  const int ti = blockIdx.y * 64, tj = blockIdx.x * 64;
  {
    int r = threadIdx.x >> 2, c0 = (threadIdx.x & 3) * 16;
#pragma unroll
    for (int i = 0; i < 16; i += 4) {
      float4 v = *(const float4*)(W + (size_t)(ti + r) * 1024 + tj + c0 + i);
      t[r][c0 + i + 0] = v.x; t[r][c0 + i + 1] = v.y;
      t[r][c0 + i + 2] = v.z; t[r][c0 + i + 3] = v.w;
    }
  }
  __syncthreads();
  {
    int c = threadIdx.x >> 2, r0 = (threadIdx.x & 3) * 16;
    union { uint16_t u[16]; uint4 v[2]; } b;
#pragma unroll
    for (int i = 0; i < 16; ++i) b.u[i] = f2bf(t[r0 + i][c]);
    uint16_t* dst = Wt + (size_t)(tj + c) * 1024 + ti + r0;
    *(uint4*)dst = b.v[0];
    *(uint4*)(dst + 8) = b.v[1];
  }
}

// ---------------- 128x128-tile GEMM, BK=64, 4 waves, 3 blocks/CU (r9 best) ----------------
// LDS 48KB: A dbuf 2x16KB @0 + B single 16KB @32768 (restaged in place).
// Per K-tile(64): read B-frags -> lgkm0 -> BAR -> restage B + A(t+1) ->
// MFMA -> vmcnt(0) -> BAR (drain covered at 3 blocks/CU, m114).
// Swizzle (proven, 0 conflicts): LDS[row][u16] = G[row][u16 ^ (row&7)];
// inverse on global_load_lds SOURCE, forward on ds_read.
__global__ __launch_bounds__(256, 3) void gemm128(const uint16_t* __restrict__ A,
                                                  const uint16_t* __restrict__ Bt,
                                                  const float* __restrict__ bias,
                                                  void* __restrict__ C, int cf32) {
  __shared__ uint8_t lds[49152];
  const int tid = threadIdx.x;
  const int l = tid & 63, w = tid >> 6;
  const int wr = w >> 1, wc = w & 1;     // 2 x 2 wave grid, 64x64 per wave
  const int lc = l & 15, lq = l >> 4;

  // bijective XCD swizzle over 2048 blocks: XCD c owns m-panels [c*32,(c+1)*32)
  const int bid = blockIdx.y * 8 + blockIdx.x;
  const int swz = (bid & 7) * 256 + (bid >> 3);
  const size_t m0 = (size_t)(swz >> 3) * 128;
  const int n0 = (swz & 7) * 128;

  const uint8_t* Ab = (const uint8_t*)A + m0 * 2048;
  const uint8_t* Bb = (const uint8_t*)Bt + (size_t)n0 * 2048;

  // staging: chunk c = w*4+j = 1KB = 8 rows x 128B; lane covers 16B
  const int lrow = l >> 3;
  const int susw = ((l & 7) ^ lrow) * 16;  // inverse-swizzled source unit

  auto stageA = [&](int buf, int kt) {
#pragma unroll
    for (int j = 0; j < 4; ++j) {
      const int c = w * 4 + j;
      gload16(Ab + (size_t)(c * 8 + lrow) * 2048 + kt * 128 + susw,
              lds + buf * 16384 + c * 1024);
    }
  };
  auto stageB = [&](int kt) {
#pragma unroll
    for (int j = 0; j < 4; ++j) {
      const int c = w * 4 + j;
      gload16(Bb + (size_t)(c * 8 + lrow) * 2048 + kt * 128 + susw,
              lds + 32768 + c * 1024);
    }
  };

  auto ldsA = [&](int buf, int mi, int kk) -> bf16x8 {
    const int row = wr * 64 + mi * 16 + lc;
    const int u = ((kk * 4 + lq) ^ (row & 7)) * 16;
    return *(const bf16x8*)(lds + buf * 16384 + row * 128 + u);
  };
  auto ldsB = [&](int ni, int kk) -> bf16x8 {
    const int row = wc * 64 + ni * 16 + lc;
    const int u = ((kk * 4 + lq) ^ (row & 7)) * 16;
    return *(const bf16x8*)(lds + 32768 + row * 128 + u);
  };

  f32x4 acc[4][4] = {};

  // prologue: tile 0
  stageA(0, 0);
  stageB(0);
  asm volatile("s_waitcnt vmcnt(0)" ::: "memory");
  BARRIER();

  for (int t = 0; t < 16; ++t) {
    const int cur = t & 1;
    const bool more = (t + 1 < 16);

    // read ALL B-frags to regs (B buffer is restaged in place below)
    bf16x8 bF[4][2];
#pragma unroll
    for (int ni = 0; ni < 4; ++ni)
#pragma unroll
      for (int kk = 0; kk < 2; ++kk) bF[ni][kk] = ldsB(ni, kk);
    LGKM0_FENCE();
    BARRIER();   // every wave's B-reads complete before any restage lands

    if (more) {
      stageB(t + 1);            // in-place (safe: B now in regs block-wide)
      stageA(cur ^ 1, t + 1);   // alt buffer
    }

#pragma unroll
    for (int kk = 0; kk < 2; ++kk) {
      bf16x8 aF[4];
#pragma unroll
      for (int mi = 0; mi < 4; ++mi) aF[mi] = ldsA(cur, mi, kk);
      __builtin_amdgcn_s_setprio(1);
#pragma unroll
      for (int mi = 0; mi < 4; ++mi)
#pragma unroll
        for (int ni = 0; ni < 4; ++ni)
          acc[mi][ni] = MFMA16(aF[mi], bF[ni][kk], acc[mi][ni]);
      __builtin_amdgcn_s_setprio(0);
    }

    if (more) {
      asm volatile("s_waitcnt vmcnt(0)" ::: "memory");  // t+1 tiles landed
      BARRIER();
    }
  }

  // epilogue: bias + store (plain per-lane; r14's LDS repack was neutral-neg)
#pragma unroll
  for (int mi = 0; mi < 4; ++mi) {
#pragma unroll
    for (int ni = 0; ni < 4; ++ni) {
      const int col = n0 + wc * 64 + ni * 16 + lc;
      const float bb = bias[col];
#pragma unroll
      for (int r = 0; r < 4; ++r) {
        const size_t row = m0 + wr * 64 + mi * 16 + lq * 4 + r;
        const float vv = acc[mi][ni][r] + bb;
        if (cf32) ((float*)C)[row * 1024 + col] = vv;
        else      ((uint16_t*)C)[row * 1024 + col] = f2bf(vv);
      }
    }
  }
}

// ---------------- block-diagonal attention (r9-proven) ----------------
__global__ __launch_bounds__(256) void attn(const uint16_t* __restrict__ Qh,
                                            const uint16_t* __restrict__ Kh,
                                            const uint16_t* __restrict__ Vh,
                                            uint16_t* __restrict__ Oh,
                                            float* __restrict__ Wlast) {
  __shared__ uint16_t Ks[128][72];
  __shared__ uint16_t Vt[64][136];
  __shared__ uint16_t Ps[128][136];

  const int blk = blockIdx.x;
  const int b = blk >> 10;
  const int h = (blk >> 6) & 15;
  const int g = blk & 63;
  const size_t rowbase = (size_t)b * 8192 + (size_t)g * 128;
  const int colbase = h * 64;

  const int tid = threadIdx.x, lane = tid & 63, wv = tid >> 6;
  const int lc = lane & 15, lq = lane >> 4;
  const int m0 = wv * 32;

  {
    const int r = tid >> 1, hf = (tid & 1) * 32;
    const uint16_t* ksrc = Kh + (rowbase + r) * 1024 + colbase + hf;
    const uint16_t* vsrc = Vh + (rowbase + r) * 1024 + colbase + hf;
    union { uint16_t u[32]; uint4 v[4]; } kk, vb;
#pragma unroll
    for (int i = 0; i < 4; ++i) kk.v[i] = *(const uint4*)(ksrc + i * 8);
#pragma unroll
    for (int i = 0; i < 4; ++i) vb.v[i] = *(const uint4*)(vsrc + i * 8);
#pragma unroll
    for (int i = 0; i < 4; ++i) *(uint4*)&Ks[r][hf + i * 8] = kk.v[i];
#pragma unroll
    for (int j = 0; j < 32; ++j) Vt[hf + j][r] = vb.u[j];
  }

  bf16x8 aq[2][2];
#pragma unroll
  for (int mi = 0; mi < 2; ++mi)
#pragma unroll
    for (int ks = 0; ks < 2; ++ks)
      aq[mi][ks] = *(const bf16x8*)(Qh + (rowbase + m0 + mi * 16 + lc) * 1024 +
                                    colbase + ks * 32 + lq * 8);

  __syncthreads();

  f32x4 sacc[2][8] = {};
#pragma unroll
  for (int ks = 0; ks < 2; ++ks) {
#pragma unroll
    for (int ni = 0; ni < 8; ++ni) {
      bf16x8 bk = *(const bf16x8*)&Ks[ni * 16 + lc][ks * 32 + lq * 8];
      sacc[0][ni] = MFMA16(aq[0][ks], bk, sacc[0][ni]);
      sacc[1][ni] = MFMA16(aq[1][ks], bk, sacc[1][ni]);
    }
  }

  const float scale = 0.125f;
  float mx[2][4], sm[2][4];
#pragma unroll
  for (int mi = 0; mi < 2; ++mi)
#pragma unroll
    for (int r = 0; r < 4; ++r) {
      float m = -1e30f;
#pragma unroll
      for (int ni = 0; ni < 8; ++ni) m = fmaxf(m, sacc[mi][ni][r]);
      m = fmaxf(m, __shfl_xor(m, 1));
      m = fmaxf(m, __shfl_xor(m, 2));
      m = fmaxf(m, __shfl_xor(m, 4));
      m = fmaxf(m, __shfl_xor(m, 8));
      mx[mi][r] = m * scale;
    }
#pragma unroll
  for (int mi = 0; mi < 2; ++mi)
#pragma unroll
    for (int ni = 0; ni < 8; ++ni)
#pragma unroll
      for (int r = 0; r < 4; ++r)
        sacc[mi][ni][r] = __expf(sacc[mi][ni][r] * scale - mx[mi][r]);
#pragma unroll
  for (int mi = 0; mi < 2; ++mi)
#pragma unroll
    for (int r = 0; r < 4; ++r) {
      float s = 0.f;
#pragma unroll
      for (int ni = 0; ni < 8; ++ni) s += sacc[mi][ni][r];
      s += __shfl_xor(s, 1); s += __shfl_xor(s, 2);
      s += __shfl_xor(s, 4); s += __shfl_xor(s, 8);
      sm[mi][r] = 1.0f / s;
    }

#pragma unroll
  for (int mi = 0; mi < 2; ++mi)
#pragma unroll
    for (int ni = 0; ni < 8; ++ni)
#pragma unroll
      for (int r = 0; r < 4; ++r) {
        float wgt = sacc[mi][ni][r] * sm[mi][r];
        sacc[mi][ni][r] = wgt;
        Ps[m0 + mi * 16 + lq * 4 + r][ni * 16 + lc] = f2bf(wgt);
      }
  if (g == 63) {
    float* wl = Wlast + (size_t)(b * 16 + h) * 16384;
#pragma unroll
    for (int mi = 0; mi < 2; ++mi)
#pragma unroll
      for (int ni = 0; ni < 8; ++ni)
#pragma unroll
        for (int r = 0; r < 4; ++r)
          wl[(size_t)(m0 + mi * 16 + lq * 4 + r) * 128 + ni * 16 + lc] =
              sacc[mi][ni][r];
  }
  __syncthreads();

  f32x4 oacc[2][4] = {};
#pragma unroll
  for (int ks = 0; ks < 4; ++ks) {
    bf16x8 ap[2], bq[4];
#pragma unroll
    for (int mi = 0; mi < 2; ++mi)
      ap[mi] = *(const bf16x8*)&Ps[m0 + mi * 16 + lc][ks * 32 + lq * 8];
#pragma unroll
    for (int ni = 0; ni < 4; ++ni)
      bq[ni] = *(const bf16x8*)&Vt[ni * 16 + lc][ks * 32 + lq * 8];
#pragma unroll
    for (int mi = 0; mi < 2; ++mi)
#pragma unroll
      for (int ni = 0; ni < 4; ++ni)
        oacc[mi][ni] = MFMA16(ap[mi], bq[ni], oacc[mi][ni]);
  }
#pragma unroll
  for (int mi = 0; mi < 2; ++mi)
#pragma unroll
    for (int ni = 0; ni < 4; ++ni)
#pragma unroll
      for (int r = 0; r < 4; ++r)
        Oh[(rowbase + m0 + mi * 16 + lq * 4 + r) * 1024 + colbase + ni * 16 + lc] =
            f2bf(oacc[mi][ni][r]);
}

extern "C" void kernel_launch(void* const* d_in, const int* in_sizes, int n_in,
                              void* d_out, int out_size, void* d_ws, size_t ws_size,
                              hipStream_t stream) {
  (void)in_sizes; (void)n_in; (void)out_size; (void)ws_size;
  const float* q  = (const float*)d_in[0];
  const float* k  = (const float*)d_in[1];
  const float* v  = (const float*)d_in[2];
  const float* Wq = (const float*)d_in[3];
  const float* bq = (const float*)d_in[4];
  const float* Wk = (const float*)d_in[5];
  const float* bk = (const float*)d_in[6];
  const float* Wv = (const float*)d_in[7];
  const float* bv = (const float*)d_in[8];
  const float* Wo = (const float*)d_in[9];
  const float* bo = (const float*)d_in[10];

  uint8_t* ws = (uint8_t*)d_ws;
  const size_t WSZ = (size_t)1024 * 1024 * 2;   // 2 MB per transposed weight
  const size_t TSZ = (size_t)32768 * 1024 * 2;  // 64 MB per bf16 activation
  uint16_t* Wtq = (uint16_t*)(ws + 0 * WSZ);
  uint16_t* Wtk = (uint16_t*)(ws + 1 * WSZ);
  uint16_t* Wtv = (uint16_t*)(ws + 2 * WSZ);
  uint16_t* Wto = (uint16_t*)(ws + 3 * WSZ);
  uint16_t* Qh  = (uint16_t*)(ws + 4 * WSZ);
  uint16_t* Khp = (uint16_t*)(ws + 4 * WSZ + 1 * TSZ);
  uint16_t* Vhp = (uint16_t*)(ws + 4 * WSZ + 2 * TSZ);
  uint16_t* Xs  = (uint16_t*)(ws + 4 * WSZ + 3 * TSZ);  // staging / attn-out

  W4 wt;
  wt.W[0] = Wq; wt.W[1] = Wk; wt.W[2] = Wv; wt.W[3] = Wo;
  wt.Wt[0] = Wtq; wt.Wt[1] = Wtk; wt.Wt[2] = Wtv; wt.Wt[3] = Wto;
  wtrans4<<<dim3(16, 16, 4), 256, 0, stream>>>(wt);

  const long NE = (long)32768 * 1024;
  const dim3 gg(8, 256), gb(256);
  cvt_bf16<<<16384, 256, 0, stream>>>(q, Xs, NE);
  gemm128<<<gg, gb, 0, stream>>>(Xs, Wtq, bq, Qh, 0);
  cvt_bf16<<<16384, 256, 0, stream>>>(k, Xs, NE);
  gemm128<<<gg, gb, 0, stream>>>(Xs, Wtk, bk, Khp, 0);
  cvt_bf16<<<16384, 256, 0, stream>>>(v, Xs, NE);
  gemm128<<<gg, gb, 0, stream>>>(Xs, Wtv, bv, Vhp, 0);

  float* outp = (float*)d_out;
  attn<<<4096, 256, 0, stream>>>(Qh, Khp, Vhp, Xs, outp + (size_t)32768 * 1024);
  gemm128<<<gg, gb, 0, stream>>>(Xs, Wto, bo, outp, 1);
}